// Round 1
// baseline (1952.144 us; speedup 1.0000x reference)
//
#include <hip/hip_runtime.h>
#include <hip/hip_bf16.h>
#include <stdint.h>

// Problem constants (CorrelationModule): x[8,384,48,48], O=512, N=48*48=2304
#define B_    8
#define CIN   384
#define OCH   512
#define NTOK  2304
#define SCALE 0.044194173824159216f  // 1/sqrt(512)

// ---------- bf16 helpers (bit-level, RNE) ----------
__device__ __forceinline__ float bf2f(uint16_t u) {
    union { uint32_t i; float f; } v; v.i = ((uint32_t)u) << 16; return v.f;
}
__device__ __forceinline__ uint16_t f2bf(float f) {
    union { uint32_t i; float f; } v; v.f = f;
    uint32_t r = v.i + 0x7fffu + ((v.i >> 16) & 1u);
    return (uint16_t)(r >> 16);
}
__device__ __forceinline__ float bflo(uint32_t u) {
    union { uint32_t i; float f; } v; v.i = u << 16; return v.f;
}
__device__ __forceinline__ float bfhi(uint32_t u) {
    union { uint32_t i; float f; } v; v.i = u & 0xffff0000u; return v.f;
}

// =====================================================================
// Kernel 1: QKV projection.  For each b, which in {q,k,v}:
//   Out[o][n] = sum_c W[o][c] * X[c][n] + bias[o]   (store bf16, [B,O,N])
// Tile 64x64, K-chunk 16, 256 threads, 4x4 microtile, fp32 accumulate.
// =====================================================================
__global__ __launch_bounds__(256) void qkv_kernel(
    const float* __restrict__ x,
    const float* __restrict__ Wq, const float* __restrict__ bq,
    const float* __restrict__ Wk, const float* __restrict__ bk,
    const float* __restrict__ Wv, const float* __restrict__ bv,
    uint16_t* __restrict__ Qw, uint16_t* __restrict__ Kw, uint16_t* __restrict__ Vw)
{
    const int n0 = blockIdx.x * 64;
    const int m0 = blockIdx.y * 64;
    const int z  = blockIdx.z;            // b*3 + which
    const int b  = z / 3, which = z % 3;
    const float* W    = (which == 0) ? Wq : (which == 1) ? Wk : Wv;
    const float* bias = (which == 0) ? bq : (which == 1) ? bk : bv;
    uint16_t*    Out  = (which == 0) ? Qw : (which == 1) ? Kw : Vw;
    const float* X = x + (size_t)b * CIN * NTOK;

    __shared__ float As[16][68];   // As[k][m] = W[m0+m][k0+k]
    __shared__ float Bs[16][68];   // Bs[k][n] = X[k0+k][n0+n]

    const int t  = threadIdx.x;
    const int tx = t & 15, ty = t >> 4;
    float acc[4][4] = {};

    const int a_m = t >> 2, a_k4 = (t & 3) * 4;    // A loader: 64 rows x 16 k
    const int b_k = t >> 4, b_n4 = (t & 15) * 4;   // B loader: 16 rows x 64 n

    for (int k0 = 0; k0 < CIN; k0 += 16) {
        float4 av  = *(const float4*)(W + (size_t)(m0 + a_m) * CIN + k0 + a_k4);
        float4 bv4 = *(const float4*)(X + (size_t)(k0 + b_k) * NTOK + n0 + b_n4);
        As[a_k4 + 0][a_m] = av.x;
        As[a_k4 + 1][a_m] = av.y;
        As[a_k4 + 2][a_m] = av.z;
        As[a_k4 + 3][a_m] = av.w;
        *(float4*)&Bs[b_k][b_n4] = bv4;
        __syncthreads();
#pragma unroll
        for (int kk = 0; kk < 16; ++kk) {
            float4 a4 = *(const float4*)&As[kk][ty * 4];
            float4 b4 = *(const float4*)&Bs[kk][tx * 4];
            float a[4] = {a4.x, a4.y, a4.z, a4.w};
            float c[4] = {b4.x, b4.y, b4.z, b4.w};
#pragma unroll
            for (int i = 0; i < 4; ++i)
#pragma unroll
                for (int j = 0; j < 4; ++j)
                    acc[i][j] += a[i] * c[j];
        }
        __syncthreads();
    }

    uint16_t* outp = Out + (size_t)b * OCH * NTOK;
#pragma unroll
    for (int i = 0; i < 4; ++i) {
        const int m = m0 + ty * 4 + i;
        const float bs = bias[m];
#pragma unroll
        for (int j = 0; j < 4; ++j) {
            const int n = n0 + tx * 4 + j;
            outp[(size_t)m * NTOK + n] = f2bf(acc[i][j] + bs);
        }
    }
}

// =====================================================================
// Kernel 2: logits  S[b][n][m] = scale * sum_o Q[b][o][n] * K[b][o][m]
// Both operands stored [O][N]: contraction dim is the row -> natural loads.
// =====================================================================
__global__ __launch_bounds__(256) void logits_kernel(
    const uint16_t* __restrict__ Qw, const uint16_t* __restrict__ Kw,
    uint16_t* __restrict__ Sw)
{
    const int mcol0 = blockIdx.x * 64;
    const int nrow0 = blockIdx.y * 64;
    const int b = blockIdx.z;
    const uint16_t* Q  = Qw + (size_t)b * OCH * NTOK;
    const uint16_t* Kp = Kw + (size_t)b * OCH * NTOK;

    __shared__ uint16_t As[16][72];  // As[o][n]
    __shared__ uint16_t Bs[16][72];  // Bs[o][m]

    const int t = threadIdx.x;
    const int tx = t & 15, ty = t >> 4;
    float acc[4][4] = {};
    const int l_k = t >> 4, l_n4 = (t & 15) * 4;

    for (int k0 = 0; k0 < OCH; k0 += 16) {
        uint2 av = *(const uint2*)(Q  + (size_t)(k0 + l_k) * NTOK + nrow0 + l_n4);
        uint2 bv = *(const uint2*)(Kp + (size_t)(k0 + l_k) * NTOK + mcol0 + l_n4);
        *(uint2*)&As[l_k][l_n4] = av;
        *(uint2*)&Bs[l_k][l_n4] = bv;
        __syncthreads();
#pragma unroll
        for (int kk = 0; kk < 16; ++kk) {
            uint2 a2 = *(const uint2*)&As[kk][ty * 4];
            uint2 b2 = *(const uint2*)&Bs[kk][tx * 4];
            float a[4], c[4];
            a[0] = bflo(a2.x); a[1] = bfhi(a2.x); a[2] = bflo(a2.y); a[3] = bfhi(a2.y);
            c[0] = bflo(b2.x); c[1] = bfhi(b2.x); c[2] = bflo(b2.y); c[3] = bfhi(b2.y);
#pragma unroll
            for (int i = 0; i < 4; ++i)
#pragma unroll
                for (int j = 0; j < 4; ++j)
                    acc[i][j] += a[i] * c[j];
        }
        __syncthreads();
    }

    uint16_t* S = Sw + (size_t)b * NTOK * NTOK;
#pragma unroll
    for (int i = 0; i < 4; ++i)
#pragma unroll
        for (int j = 0; j < 4; ++j)
            S[(size_t)(nrow0 + ty * 4 + i) * NTOK + mcol0 + tx * 4 + j] =
                f2bf(acc[i][j] * SCALE);
}

// =====================================================================
// Kernel 3: row softmax, in place over S[b][n][:], one block per row.
// =====================================================================
__global__ __launch_bounds__(256) void softmax_kernel(uint16_t* __restrict__ Sw)
{
    uint16_t* Srow = Sw + (size_t)blockIdx.x * NTOK;
    const int t = threadIdx.x;
    const int wave = t >> 6, lane = t & 63;
    __shared__ float redmax[4];
    __shared__ float redsum[4];

    float v[9];
    float mx = -1e30f;
#pragma unroll
    for (int i = 0; i < 9; ++i) {
        v[i] = bf2f(Srow[t + i * 256]);
        mx = fmaxf(mx, v[i]);
    }
#pragma unroll
    for (int off = 32; off; off >>= 1) mx = fmaxf(mx, __shfl_xor(mx, off));
    if (lane == 0) redmax[wave] = mx;
    __syncthreads();
    mx = fmaxf(fmaxf(redmax[0], redmax[1]), fmaxf(redmax[2], redmax[3]));

    float sum = 0.f;
#pragma unroll
    for (int i = 0; i < 9; ++i) { v[i] = __expf(v[i] - mx); sum += v[i]; }
#pragma unroll
    for (int off = 32; off; off >>= 1) sum += __shfl_xor(sum, off);
    if (lane == 0) redsum[wave] = sum;
    __syncthreads();
    sum = redsum[0] + redsum[1] + redsum[2] + redsum[3];
    const float inv = 1.0f / sum;
#pragma unroll
    for (int i = 0; i < 9; ++i) Srow[t + i * 256] = f2bf(v[i] * inv);
}

// =====================================================================
// Kernel 4: PV.  AO[b][o][n] = sum_m V[b][o][m] * P[b][n][m]
// A = V (rows o, k = m, natural row-major, transpose-on-store to LDS);
// B = P^T (rows n read row-major, transpose-on-store).
// =====================================================================
__global__ __launch_bounds__(256) void pv_kernel(
    const uint16_t* __restrict__ Vw, const uint16_t* __restrict__ Pw,
    uint16_t* __restrict__ AOw)
{
    const int n0 = blockIdx.x * 64;
    const int o0 = blockIdx.y * 64;
    const int b = blockIdx.z;
    const uint16_t* V = Vw + (size_t)b * OCH * NTOK;
    const uint16_t* P = Pw + (size_t)b * NTOK * NTOK;

    __shared__ uint16_t As[16][72];  // As[m][o]
    __shared__ uint16_t Bs[16][72];  // Bs[m][n]

    const int t = threadIdx.x;
    const int tx = t & 15, ty = t >> 4;
    float acc[4][4] = {};
    const int r = t >> 2, k4 = (t & 3) * 4;   // 64 rows x 16 k

    for (int k0 = 0; k0 < NTOK; k0 += 16) {
        uint2 av = *(const uint2*)(V + (size_t)(o0 + r) * NTOK + k0 + k4);
        uint2 bv = *(const uint2*)(P + (size_t)(n0 + r) * NTOK + k0 + k4);
        As[k4 + 0][r] = (uint16_t)(av.x & 0xffffu);
        As[k4 + 1][r] = (uint16_t)(av.x >> 16);
        As[k4 + 2][r] = (uint16_t)(av.y & 0xffffu);
        As[k4 + 3][r] = (uint16_t)(av.y >> 16);
        Bs[k4 + 0][r] = (uint16_t)(bv.x & 0xffffu);
        Bs[k4 + 1][r] = (uint16_t)(bv.x >> 16);
        Bs[k4 + 2][r] = (uint16_t)(bv.y & 0xffffu);
        Bs[k4 + 3][r] = (uint16_t)(bv.y >> 16);
        __syncthreads();
#pragma unroll
        for (int kk = 0; kk < 16; ++kk) {
            uint2 a2 = *(const uint2*)&As[kk][ty * 4];
            uint2 b2 = *(const uint2*)&Bs[kk][tx * 4];
            float a[4], c[4];
            a[0] = bflo(a2.x); a[1] = bfhi(a2.x); a[2] = bflo(a2.y); a[3] = bfhi(a2.y);
            c[0] = bflo(b2.x); c[1] = bfhi(b2.x); c[2] = bflo(b2.y); c[3] = bfhi(b2.y);
#pragma unroll
            for (int i = 0; i < 4; ++i)
#pragma unroll
                for (int j = 0; j < 4; ++j)
                    acc[i][j] += a[i] * c[j];
        }
        __syncthreads();
    }

    uint16_t* AO = AOw + (size_t)b * OCH * NTOK;
#pragma unroll
    for (int i = 0; i < 4; ++i)
#pragma unroll
        for (int j = 0; j < 4; ++j)
            AO[(size_t)(o0 + ty * 4 + i) * NTOK + n0 + tx * 4 + j] = f2bf(acc[i][j]);
}

// =====================================================================
// Kernel 5: output projection.
//   out[b][p][n] = sum_o Wo[p][o] * AO[b][o][n] + bo[p]   (fp32 out)
// =====================================================================
__global__ __launch_bounds__(256) void out_kernel(
    const float* __restrict__ Wo, const float* __restrict__ bo,
    const uint16_t* __restrict__ AOw, float* __restrict__ out)
{
    const int n0 = blockIdx.x * 64;
    const int p0 = blockIdx.y * 64;
    const int b = blockIdx.z;
    const uint16_t* AO = AOw + (size_t)b * OCH * NTOK;

    __shared__ float    As[16][68];  // As[o][p] = Wo[p0+p][k0+o]
    __shared__ uint16_t Bs[16][72];  // Bs[o][n] = AO[k0+o][n0+n]

    const int t = threadIdx.x;
    const int tx = t & 15, ty = t >> 4;
    float acc[4][4] = {};
    const int a_m = t >> 2, a_k4 = (t & 3) * 4;
    const int b_k = t >> 4, b_n4 = (t & 15) * 4;

    for (int k0 = 0; k0 < OCH; k0 += 16) {
        float4 av = *(const float4*)(Wo + (size_t)(p0 + a_m) * OCH + k0 + a_k4);
        uint2  bv = *(const uint2*)(AO + (size_t)(k0 + b_k) * NTOK + n0 + b_n4);
        As[a_k4 + 0][a_m] = av.x;
        As[a_k4 + 1][a_m] = av.y;
        As[a_k4 + 2][a_m] = av.z;
        As[a_k4 + 3][a_m] = av.w;
        *(uint2*)&Bs[b_k][b_n4] = bv;
        __syncthreads();
#pragma unroll
        for (int kk = 0; kk < 16; ++kk) {
            float4 a4 = *(const float4*)&As[kk][ty * 4];
            uint2  b2 = *(const uint2*)&Bs[kk][tx * 4];
            float a[4] = {a4.x, a4.y, a4.z, a4.w};
            float c[4];
            c[0] = bflo(b2.x); c[1] = bfhi(b2.x); c[2] = bflo(b2.y); c[3] = bfhi(b2.y);
#pragma unroll
            for (int i = 0; i < 4; ++i)
#pragma unroll
                for (int j = 0; j < 4; ++j)
                    acc[i][j] += a[i] * c[j];
        }
        __syncthreads();
    }

    float* outp = out + (size_t)b * OCH * NTOK;
#pragma unroll
    for (int i = 0; i < 4; ++i) {
        const int p = p0 + ty * 4 + i;
        const float bs = bo[p];
#pragma unroll
        for (int j = 0; j < 4; ++j)
            outp[(size_t)p * NTOK + n0 + tx * 4 + j] = acc[i][j] + bs;
    }
}

// =====================================================================
extern "C" void kernel_launch(void* const* d_in, const int* in_sizes, int n_in,
                              void* d_out, int out_size, void* d_ws, size_t ws_size,
                              hipStream_t stream)
{
    const float* x  = (const float*)d_in[0];
    const float* Wq = (const float*)d_in[1];
    const float* bq = (const float*)d_in[2];
    const float* Wk = (const float*)d_in[3];
    const float* bk = (const float*)d_in[4];
    const float* Wv = (const float*)d_in[5];
    const float* bv = (const float*)d_in[6];
    const float* Wo = (const float*)d_in[7];
    const float* bo = (const float*)d_in[8];
    float* out = (float*)d_out;

    // workspace layout (bf16 elements): Q,K,V [B,O,N]; S/P [B,N,N]; AO [B,O,N]
    uint16_t* ws = (uint16_t*)d_ws;
    const size_t qkvsz = (size_t)B_ * OCH * NTOK;     // 9,437,184
    uint16_t* Qw  = ws;
    uint16_t* Kw  = Qw + qkvsz;
    uint16_t* Vw  = Kw + qkvsz;
    uint16_t* Sw  = Vw + qkvsz;                        // B*N*N = 42,467,328
    uint16_t* AOw = Sw + (size_t)B_ * NTOK * NTOK;
    // total = 160.4 MB of d_ws

    dim3 blk(256);
    qkv_kernel<<<dim3(NTOK / 64, OCH / 64, 3 * B_), blk, 0, stream>>>(
        x, Wq, bq, Wk, bk, Wv, bv, Qw, Kw, Vw);
    logits_kernel<<<dim3(NTOK / 64, NTOK / 64, B_), blk, 0, stream>>>(Qw, Kw, Sw);
    softmax_kernel<<<dim3(B_ * NTOK), blk, 0, stream>>>(Sw);
    pv_kernel<<<dim3(NTOK / 64, OCH / 64, B_), blk, 0, stream>>>(Vw, Sw, AOw);
    out_kernel<<<dim3(NTOK / 64, OCH / 64, B_), blk, 0, stream>>>(Wo, bo, AOw, out);
}

// Round 2
// 587.316 us; speedup vs baseline: 3.3238x; 3.3238x over previous
//
#include <hip/hip_runtime.h>
#include <hip/hip_bf16.h>
#include <stdint.h>

// Problem constants (CorrelationModule): x[8,384,48,48], O=512, N=48*48=2304
#define B_    8
#define CIN   384
#define OCH   512
#define NTOK  2304
#define SCALE 0.044194173824159216f  // 1/sqrt(512)

typedef unsigned short u16;
typedef u16   u16x8 __attribute__((ext_vector_type(8)));
typedef u16   u16x4 __attribute__((ext_vector_type(4)));
typedef short s16x8 __attribute__((ext_vector_type(8)));
typedef float f32x4 __attribute__((ext_vector_type(4)));

#define BKP 40   // LDS row pitch for 32-k tiles (pad 32->40: b128 reads 2-way only)

// ---------- bf16 helpers (bit-level, RNE) ----------
__device__ __forceinline__ float bf2f(u16 u) {
    union { uint32_t i; float f; } v; v.i = ((uint32_t)u) << 16; return v.f;
}
__device__ __forceinline__ u16 f2bf(float f) {
    union { uint32_t i; float f; } v; v.f = f;
    uint32_t r = v.i + 0x7fffu + ((v.i >> 16) & 1u);
    return (u16)(r >> 16);
}

// =====================================================================
// Shared MFMA-GEMM pieces: 128x128 block tile, BK=32, 256 thr = 4 waves
// (2x2 of 64x64). LDS tiles stored [free_dim][k] so both A and B
// fragments are single ds_read_b128s.
// =====================================================================

// stage a 128x32 bf16 tile (row-major src, leading dim ld) into dst[128][BKP]
__device__ __forceinline__ void stage_bf16(const u16* __restrict__ src, int ld,
                                           u16 (* __restrict__ dst)[BKP], int t)
{
#pragma unroll
    for (int rep = 0; rep < 2; ++rep) {
        const int idx = t + rep * 256;
        const int c = (idx & 3) * 8;
        const int r = idx >> 2;
        u16x8 v = *(const u16x8*)(src + (size_t)r * ld + c);
        *(u16x8*)&dst[r][c] = v;
    }
}

// stage a 128x32 fp32 tile with conversion to bf16
__device__ __forceinline__ void stage_f32(const float* __restrict__ src, int ld,
                                          u16 (* __restrict__ dst)[BKP], int t)
{
#pragma unroll
    for (int rep = 0; rep < 4; ++rep) {
        const int idx = t + rep * 256;
        const int c = (idx & 7) * 4;
        const int r = idx >> 3;
        float4 v = *(const float4*)(src + (size_t)r * ld + c);
        u16x4 o;
        o.x = f2bf(v.x); o.y = f2bf(v.y); o.z = f2bf(v.z); o.w = f2bf(v.w);
        *(u16x4*)&dst[r][c] = o;
    }
}

__device__ __forceinline__ void mfma_core(const u16 (* __restrict__ As)[BKP],
                                          const u16 (* __restrict__ Bs)[BKP],
                                          int wm, int wn, int lrow, int kq,
                                          f32x4 acc[4][4])
{
    s16x8 a[4], b[4];
#pragma unroll
    for (int i = 0; i < 4; ++i)
        a[i] = *(const s16x8*)&As[wm + i * 16 + lrow][kq * 8];
#pragma unroll
    for (int j = 0; j < 4; ++j)
        b[j] = *(const s16x8*)&Bs[wn + j * 16 + lrow][kq * 8];
#pragma unroll
    for (int i = 0; i < 4; ++i)
#pragma unroll
        for (int j = 0; j < 4; ++j)
            acc[i][j] = __builtin_amdgcn_mfma_f32_16x16x32_bf16(a[i], b[j], acc[i][j], 0, 0, 0);
}

// =====================================================================
// Kernel 1: QKV projection (fp32 VALU, 64x64 tile). Writes:
//   Qt[b][n][o], Kt[b][m][o]  (token-major, via LDS transpose epilogue)
//   V [b][o][m]               (channel-major, direct)
// =====================================================================
__global__ __launch_bounds__(256) void qkv_kernel(
    const float* __restrict__ x,
    const float* __restrict__ Wq, const float* __restrict__ bq,
    const float* __restrict__ Wk, const float* __restrict__ bk,
    const float* __restrict__ Wv, const float* __restrict__ bv,
    u16* __restrict__ Qt, u16* __restrict__ Kt, u16* __restrict__ Vw)
{
    const int n0 = blockIdx.x * 64;
    const int m0 = blockIdx.y * 64;
    const int z  = blockIdx.z;            // b*3 + which
    const int b  = z / 3, which = z % 3;
    const float* W    = (which == 0) ? Wq : (which == 1) ? Wk : Wv;
    const float* bias = (which == 0) ? bq : (which == 1) ? bk : bv;
    const float* X = x + (size_t)b * CIN * NTOK;

    __shared__ float As[16][68];   // As[k][m] = W[m0+m][k0+k]
    __shared__ float Bs[16][68];   // Bs[k][n] = X[k0+k][n0+n]
    __shared__ u16   Ts[64][65];   // transpose scratch (pitch 65: conflict-free-ish)

    const int t  = threadIdx.x;
    const int tx = t & 15, ty = t >> 4;
    float acc[4][4] = {};

    const int a_m = t >> 2, a_k4 = (t & 3) * 4;
    const int b_k = t >> 4, b_n4 = (t & 15) * 4;

    for (int k0 = 0; k0 < CIN; k0 += 16) {
        float4 av  = *(const float4*)(W + (size_t)(m0 + a_m) * CIN + k0 + a_k4);
        float4 bv4 = *(const float4*)(X + (size_t)(k0 + b_k) * NTOK + n0 + b_n4);
        As[a_k4 + 0][a_m] = av.x;
        As[a_k4 + 1][a_m] = av.y;
        As[a_k4 + 2][a_m] = av.z;
        As[a_k4 + 3][a_m] = av.w;
        *(float4*)&Bs[b_k][b_n4] = bv4;
        __syncthreads();
#pragma unroll
        for (int kk = 0; kk < 16; ++kk) {
            float4 a4 = *(const float4*)&As[kk][ty * 4];
            float4 b4 = *(const float4*)&Bs[kk][tx * 4];
            float a[4] = {a4.x, a4.y, a4.z, a4.w};
            float c[4] = {b4.x, b4.y, b4.z, b4.w};
#pragma unroll
            for (int i = 0; i < 4; ++i)
#pragma unroll
                for (int j = 0; j < 4; ++j)
                    acc[i][j] += a[i] * c[j];
        }
        __syncthreads();
    }

    if (which == 2) {
        // V stays [O][N]
        u16* outp = Vw + (size_t)b * OCH * NTOK;
#pragma unroll
        for (int i = 0; i < 4; ++i) {
            const int m = m0 + ty * 4 + i;
            const float bs = bias[m];
#pragma unroll
            for (int j = 0; j < 4; ++j)
                outp[(size_t)m * NTOK + n0 + tx * 4 + j] = f2bf(acc[i][j] + bs);
        }
    } else {
        // Q/K go out token-major [N][O]: transpose 64x64 tile through LDS
#pragma unroll
        for (int i = 0; i < 4; ++i) {
            const float bs = bias[m0 + ty * 4 + i];
#pragma unroll
            for (int j = 0; j < 4; ++j)
                Ts[tx * 4 + j][ty * 4 + i] = f2bf(acc[i][j] + bs);
        }
        __syncthreads();
        u16* outp = ((which == 0) ? Qt : Kt) + (size_t)b * NTOK * OCH;
        const int r = t >> 2;
#pragma unroll
        for (int rep = 0; rep < 2; ++rep) {
            const int c = (t & 3) * 8 + rep * 32;
            u16 tmp[8];
#pragma unroll
            for (int jj = 0; jj < 8; ++jj) tmp[jj] = Ts[r][c + jj];
            *(u16x8*)(outp + (size_t)(n0 + r) * OCH + m0 + c) = *(const u16x8*)tmp;
        }
    }
}

// =====================================================================
// Kernel 2 (MFMA): logits S[b][n][m] = scale * sum_o Qt[n][o]*Kt[m][o]
// M-dim = n, N-dim = m, K = OCH. Both operands natural [token][o].
// =====================================================================
__global__ __launch_bounds__(256) void logits_kernel(
    const u16* __restrict__ Qt, const u16* __restrict__ Kt,
    u16* __restrict__ Sw)
{
    const int mcol0 = blockIdx.x * 128;
    const int nrow0 = blockIdx.y * 128;
    const int b = blockIdx.z;
    const u16* Abase = Qt + (size_t)b * NTOK * OCH + (size_t)nrow0 * OCH;
    const u16* Bbase = Kt + (size_t)b * NTOK * OCH + (size_t)mcol0 * OCH;

    __shared__ u16 As[128][BKP];
    __shared__ u16 Bs[128][BKP];

    const int t = threadIdx.x;
    const int w = t >> 6, ln = t & 63;
    const int wm = (w & 1) * 64, wn = (w >> 1) * 64;
    const int lrow = ln & 15, kq = ln >> 4;

    f32x4 acc[4][4] = {};

    for (int k0 = 0; k0 < OCH; k0 += 32) {
        stage_bf16(Abase + k0, OCH, As, t);
        stage_bf16(Bbase + k0, OCH, Bs, t);
        __syncthreads();
        mfma_core(As, Bs, wm, wn, lrow, kq, acc);
        __syncthreads();
    }

    u16* S = Sw + (size_t)b * NTOK * NTOK;
#pragma unroll
    for (int i = 0; i < 4; ++i) {
        const int row = nrow0 + wm + i * 16 + kq * 4;
#pragma unroll
        for (int j = 0; j < 4; ++j) {
            const int col = mcol0 + wn + j * 16 + lrow;
#pragma unroll
            for (int r = 0; r < 4; ++r)
                S[(size_t)(row + r) * NTOK + col] = f2bf(acc[i][j][r] * SCALE);
        }
    }
}

// =====================================================================
// Kernel 3: row softmax in place over S[b][n][:], one block per row.
// =====================================================================
__global__ __launch_bounds__(256) void softmax_kernel(u16* __restrict__ Sw)
{
    u16* Srow = Sw + (size_t)blockIdx.x * NTOK;
    const int t = threadIdx.x;
    const int wave = t >> 6, lane = t & 63;
    __shared__ float redmax[4];
    __shared__ float redsum[4];

    float v[9];
    float mx = -1e30f;
#pragma unroll
    for (int i = 0; i < 9; ++i) {
        v[i] = bf2f(Srow[t + i * 256]);
        mx = fmaxf(mx, v[i]);
    }
#pragma unroll
    for (int off = 32; off; off >>= 1) mx = fmaxf(mx, __shfl_xor(mx, off));
    if (lane == 0) redmax[wave] = mx;
    __syncthreads();
    mx = fmaxf(fmaxf(redmax[0], redmax[1]), fmaxf(redmax[2], redmax[3]));

    float sum = 0.f;
#pragma unroll
    for (int i = 0; i < 9; ++i) { v[i] = __expf(v[i] - mx); sum += v[i]; }
#pragma unroll
    for (int off = 32; off; off >>= 1) sum += __shfl_xor(sum, off);
    if (lane == 0) redsum[wave] = sum;
    __syncthreads();
    sum = redsum[0] + redsum[1] + redsum[2] + redsum[3];
    const float inv = 1.0f / sum;
#pragma unroll
    for (int i = 0; i < 9; ++i) Srow[t + i * 256] = f2bf(v[i] * inv);
}

// =====================================================================
// Kernel 4 (MFMA): PV, transposed output.
//   AOt[b][n][o] = sum_m P[n][m] * V[o][m]
// M-dim = n (A = P natural), N-dim = o (B = V natural), K = NTOK.
// =====================================================================
__global__ __launch_bounds__(256) void pv_kernel(
    const u16* __restrict__ Pw, const u16* __restrict__ Vw,
    u16* __restrict__ AOt)
{
    const int nrow0 = blockIdx.x * 128;   // token rows
    const int ocol0 = blockIdx.y * 128;   // channel cols
    const int b = blockIdx.z;
    const u16* Abase = Pw + (size_t)b * NTOK * NTOK + (size_t)nrow0 * NTOK;
    const u16* Bbase = Vw + (size_t)b * OCH * NTOK + (size_t)ocol0 * NTOK;

    __shared__ u16 As[128][BKP];
    __shared__ u16 Bs[128][BKP];

    const int t = threadIdx.x;
    const int w = t >> 6, ln = t & 63;
    const int wm = (w & 1) * 64, wn = (w >> 1) * 64;
    const int lrow = ln & 15, kq = ln >> 4;

    f32x4 acc[4][4] = {};

    for (int k0 = 0; k0 < NTOK; k0 += 32) {
        stage_bf16(Abase + k0, NTOK, As, t);
        stage_bf16(Bbase + k0, NTOK, Bs, t);
        __syncthreads();
        mfma_core(As, Bs, wm, wn, lrow, kq, acc);
        __syncthreads();
    }

    u16* AO = AOt + (size_t)b * NTOK * OCH;
#pragma unroll
    for (int i = 0; i < 4; ++i) {
        const int row = nrow0 + wm + i * 16 + kq * 4;    // token n
#pragma unroll
        for (int j = 0; j < 4; ++j) {
            const int col = ocol0 + wn + j * 16 + lrow;  // channel o
#pragma unroll
            for (int r = 0; r < 4; ++r)
                AO[(size_t)(row + r) * OCH + col] = f2bf(acc[i][j][r]);
        }
    }
}

// =====================================================================
// Kernel 5 (MFMA): output projection (fp32 out).
//   out[b][p][n] = sum_o Wo[p][o] * AOt[n][o] + bo[p]
// M-dim = p (A = Wo, fp32->bf16 on stage), N-dim = n (B = AOt natural).
// =====================================================================
__global__ __launch_bounds__(256) void out_kernel(
    const float* __restrict__ Wo, const float* __restrict__ bo,
    const u16* __restrict__ AOt, float* __restrict__ out)
{
    const int p0 = blockIdx.x * 128;
    const int n0 = blockIdx.y * 128;
    const int b = blockIdx.z;
    const float* Abase = Wo + (size_t)p0 * OCH;
    const u16*   Bbase = AOt + (size_t)b * NTOK * OCH + (size_t)n0 * OCH;

    __shared__ u16 As[128][BKP];
    __shared__ u16 Bs[128][BKP];

    const int t = threadIdx.x;
    const int w = t >> 6, ln = t & 63;
    const int wm = (w & 1) * 64, wn = (w >> 1) * 64;
    const int lrow = ln & 15, kq = ln >> 4;

    f32x4 acc[4][4] = {};

    for (int k0 = 0; k0 < OCH; k0 += 32) {
        stage_f32(Abase + k0, OCH, As, t);
        stage_bf16(Bbase + k0, OCH, Bs, t);
        __syncthreads();
        mfma_core(As, Bs, wm, wn, lrow, kq, acc);
        __syncthreads();
    }

    float* outp = out + (size_t)b * OCH * NTOK;
#pragma unroll
    for (int i = 0; i < 4; ++i) {
        const int prow = p0 + wm + i * 16 + kq * 4;
#pragma unroll
        for (int r = 0; r < 4; ++r) {
            const float bs = bo[prow + r];
#pragma unroll
            for (int j = 0; j < 4; ++j) {
                const int col = n0 + wn + j * 16 + lrow;
                outp[(size_t)(prow + r) * NTOK + col] = acc[i][j][r] + bs;
            }
        }
    }
}

// =====================================================================
extern "C" void kernel_launch(void* const* d_in, const int* in_sizes, int n_in,
                              void* d_out, int out_size, void* d_ws, size_t ws_size,
                              hipStream_t stream)
{
    const float* x  = (const float*)d_in[0];
    const float* Wq = (const float*)d_in[1];
    const float* bq = (const float*)d_in[2];
    const float* Wk = (const float*)d_in[3];
    const float* bk = (const float*)d_in[4];
    const float* Wv = (const float*)d_in[5];
    const float* bv = (const float*)d_in[6];
    const float* Wo = (const float*)d_in[7];
    const float* bo = (const float*)d_in[8];
    float* out = (float*)d_out;

    // workspace (bf16): Qt,Kt [B,N,O]; V [B,O,N]; S/P [B,N,N]; AOt [B,N,O]
    u16* ws = (u16*)d_ws;
    const size_t qkvsz = (size_t)B_ * OCH * NTOK;     // 9,437,184 elems
    u16* Qt  = ws;
    u16* Kt  = Qt + qkvsz;
    u16* Vw  = Kt + qkvsz;
    u16* Sw  = Vw + qkvsz;                            // B*N*N elems
    u16* AOt = Sw + (size_t)B_ * NTOK * NTOK;
    // total = 160.4 MB

    dim3 blk(256);
    qkv_kernel<<<dim3(NTOK / 64, OCH / 64, 3 * B_), blk, 0, stream>>>(
        x, Wq, bq, Wk, bk, Wv, bv, Qt, Kt, Vw);
    logits_kernel<<<dim3(NTOK / 128, NTOK / 128, B_), blk, 0, stream>>>(Qt, Kt, Sw);
    softmax_kernel<<<dim3(B_ * NTOK), blk, 0, stream>>>(Sw);
    pv_kernel<<<dim3(NTOK / 128, OCH / 128, B_), blk, 0, stream>>>(Sw, Vw, AOt);
    out_kernel<<<dim3(OCH / 128, NTOK / 128, B_), blk, 0, stream>>>(Wo, bo, AOt, out);
}

// Round 3
// 374.101 us; speedup vs baseline: 5.2182x; 1.5699x over previous
//
#include <hip/hip_runtime.h>
#include <hip/hip_bf16.h>
#include <stdint.h>

// Problem constants (CorrelationModule): x[8,384,48,48], O=512, N=48*48=2304
#define B_    8
#define CIN   384
#define OCH   512
#define NTOK  2304
#define SCALE 0.044194173824159216f  // 1/sqrt(512)

typedef unsigned short u16;
typedef u16   u16x8 __attribute__((ext_vector_type(8)));
typedef u16   u16x4 __attribute__((ext_vector_type(4)));
typedef short s16x8 __attribute__((ext_vector_type(8)));
typedef float f32x4 __attribute__((ext_vector_type(4)));

#define BKP 40   // LDS row pitch for 32-k tiles (pad 32->40: b128 reads 2-way only)

// ---------- bf16 helpers (bit-level, RNE) ----------
__device__ __forceinline__ float bf2f(u16 u) {
    union { uint32_t i; float f; } v; v.i = ((uint32_t)u) << 16; return v.f;
}
__device__ __forceinline__ u16 f2bf(float f) {
    union { uint32_t i; float f; } v; v.f = f;
    uint32_t r = v.i + 0x7fffu + ((v.i >> 16) & 1u);
    return (u16)(r >> 16);
}

// =====================================================================
// Kernel 0a: weight cast fp32 -> bf16 (Wq, Wk, Wv: 512x384; Wo: 512x512)
// =====================================================================
#define WQKV_SZ (OCH * CIN)          // 196608
#define WO_SZ   (OCH * OCH)          // 262144
#define WTOT    (3 * WQKV_SZ + WO_SZ)

__global__ __launch_bounds__(256) void prep_w_kernel(
    const float* __restrict__ Wq, const float* __restrict__ Wk,
    const float* __restrict__ Wv, const float* __restrict__ Wo,
    u16* __restrict__ Wqb, u16* __restrict__ Wkb,
    u16* __restrict__ Wvb, u16* __restrict__ Wob)
{
    const int i4 = (blockIdx.x * 256 + threadIdx.x) * 4;
    if (i4 >= WTOT) return;
    const float* src; u16* dst; int off;
    if      (i4 < WQKV_SZ)     { src = Wq; dst = Wqb; off = i4; }
    else if (i4 < 2 * WQKV_SZ) { src = Wk; dst = Wkb; off = i4 - WQKV_SZ; }
    else if (i4 < 3 * WQKV_SZ) { src = Wv; dst = Wvb; off = i4 - 2 * WQKV_SZ; }
    else                       { src = Wo; dst = Wob; off = i4 - 3 * WQKV_SZ; }
    float4 v = *(const float4*)(src + off);
    u16x4 o;
    o.x = f2bf(v.x); o.y = f2bf(v.y); o.z = f2bf(v.z); o.w = f2bf(v.w);
    *(u16x4*)(dst + off) = o;
}

// =====================================================================
// Kernel 0b: transpose x [B,C,N] fp32 -> xT [B,N,C] bf16.  64x64 tiles.
// Phase 1: coalesced float4 reads along n, float2 LDS stores (pitch 66).
// Phase 2: scalar LDS column reads (~4-way), u16x8 coalesced writes.
// =====================================================================
__global__ __launch_bounds__(256) void transpose_x_kernel(
    const float* __restrict__ x, u16* __restrict__ xT)
{
    const int n0 = blockIdx.x * 64;
    const int c0 = blockIdx.y * 64;
    const int b  = blockIdx.z;
    const float* X = x + (size_t)b * CIN * NTOK;

    __shared__ float Ts[64][66];

    const int t = threadIdx.x;
#pragma unroll
    for (int rep = 0; rep < 4; ++rep) {
        const int cr = (t >> 4) + rep * 16;
        const int n4 = (t & 15) * 4;
        float4 v = *(const float4*)(X + (size_t)(c0 + cr) * NTOK + n0 + n4);
        *(float2*)&Ts[cr][n4]     = make_float2(v.x, v.y);
        *(float2*)&Ts[cr][n4 + 2] = make_float2(v.z, v.w);
    }
    __syncthreads();

    u16* O = xT + (size_t)b * NTOK * CIN;
#pragma unroll
    for (int rep = 0; rep < 2; ++rep) {
        const int nr = (t >> 3) + rep * 32;
        const int c8 = (t & 7) * 8;
        u16 tmp[8];
#pragma unroll
        for (int j = 0; j < 8; ++j) tmp[j] = f2bf(Ts[c8 + j][nr]);
        *(u16x8*)(O + (size_t)(n0 + nr) * CIN + c0 + c8) = *(const u16x8*)tmp;
    }
}

// =====================================================================
// Generic MFMA GEMM: C[m][n] = sum_k A[m][k] * B[n][k]  (+bias) (*scale)
// 128x128 block tile, BK=32, 256 thr = 4 waves (2x2 of 64x64).
// BIAS: 0 none, 1 bias[row], 2 bias[col].  SC: multiply by SCALE.
// =====================================================================
__device__ __forceinline__ void stage_bf16(const u16* __restrict__ src, int ld,
                                           u16 (* __restrict__ dst)[BKP], int t)
{
#pragma unroll
    for (int rep = 0; rep < 2; ++rep) {
        const int idx = t + rep * 256;
        const int c = (idx & 3) * 8;
        const int r = idx >> 2;
        u16x8 v = *(const u16x8*)(src + (size_t)r * ld + c);
        *(u16x8*)&dst[r][c] = v;
    }
}

__device__ __forceinline__ void mfma_core(const u16 (* __restrict__ As)[BKP],
                                          const u16 (* __restrict__ Bs)[BKP],
                                          int wm, int wn, int lrow, int kq,
                                          f32x4 acc[4][4])
{
    s16x8 a[4], b[4];
#pragma unroll
    for (int i = 0; i < 4; ++i)
        a[i] = *(const s16x8*)&As[wm + i * 16 + lrow][kq * 8];
#pragma unroll
    for (int j = 0; j < 4; ++j)
        b[j] = *(const s16x8*)&Bs[wn + j * 16 + lrow][kq * 8];
#pragma unroll
    for (int i = 0; i < 4; ++i)
#pragma unroll
        for (int j = 0; j < 4; ++j)
            acc[i][j] = __builtin_amdgcn_mfma_f32_16x16x32_bf16(a[i], b[j], acc[i][j], 0, 0, 0);
}

template <int BIAS, bool SC, typename OutT>
__global__ __launch_bounds__(256) void gemm_kernel(
    const u16* __restrict__ Ag, const u16* __restrict__ Bg,
    const float* __restrict__ bias, OutT* __restrict__ Cg,
    int K, int N, long sA, long sB, long sC)
{
    const int n0 = blockIdx.x * 128;
    const int m0 = blockIdx.y * 128;
    const int z  = blockIdx.z;
    const u16* A  = Ag + (size_t)z * sA + (size_t)m0 * K;
    const u16* Bp = Bg + (size_t)z * sB + (size_t)n0 * K;
    OutT* C = Cg + (size_t)z * sC;

    __shared__ u16 As[128][BKP];
    __shared__ u16 Bs[128][BKP];

    const int t = threadIdx.x;
    const int w = t >> 6, ln = t & 63;
    const int wm = (w & 1) * 64, wn = (w >> 1) * 64;
    const int lrow = ln & 15, kq = ln >> 4;

    f32x4 acc[4][4] = {};

    for (int k0 = 0; k0 < K; k0 += 32) {
        stage_bf16(A + k0, K, As, t);
        stage_bf16(Bp + k0, K, Bs, t);
        __syncthreads();
        mfma_core(As, Bs, wm, wn, lrow, kq, acc);
        __syncthreads();
    }

#pragma unroll
    for (int i = 0; i < 4; ++i) {
        const int row = m0 + wm + i * 16 + kq * 4;
#pragma unroll
        for (int r = 0; r < 4; ++r) {
            float badd = 0.f;
            if (BIAS == 1) badd = bias[row + r];
#pragma unroll
            for (int j = 0; j < 4; ++j) {
                const int col = n0 + wn + j * 16 + lrow;
                float v = acc[i][j][r];
                if (SC) v *= SCALE;
                if (BIAS == 1) v += badd;
                if (BIAS == 2) v += bias[col];
                if constexpr (sizeof(OutT) == 2)
                    C[(size_t)(row + r) * N + col] = f2bf(v);
                else
                    C[(size_t)(row + r) * N + col] = v;
            }
        }
    }
}

// =====================================================================
// Row softmax in place over S[b][n][:], one block per row.
// =====================================================================
__global__ __launch_bounds__(256) void softmax_kernel(u16* __restrict__ Sw)
{
    u16* Srow = Sw + (size_t)blockIdx.x * NTOK;
    const int t = threadIdx.x;
    const int wave = t >> 6, lane = t & 63;
    __shared__ float redmax[4];
    __shared__ float redsum[4];

    float v[9];
    float mx = -1e30f;
#pragma unroll
    for (int i = 0; i < 9; ++i) {
        v[i] = bf2f(Srow[t + i * 256]);
        mx = fmaxf(mx, v[i]);
    }
#pragma unroll
    for (int off = 32; off; off >>= 1) mx = fmaxf(mx, __shfl_xor(mx, off));
    if (lane == 0) redmax[wave] = mx;
    __syncthreads();
    mx = fmaxf(fmaxf(redmax[0], redmax[1]), fmaxf(redmax[2], redmax[3]));

    float sum = 0.f;
#pragma unroll
    for (int i = 0; i < 9; ++i) { v[i] = __expf(v[i] - mx); sum += v[i]; }
#pragma unroll
    for (int off = 32; off; off >>= 1) sum += __shfl_xor(sum, off);
    if (lane == 0) redsum[wave] = sum;
    __syncthreads();
    sum = redsum[0] + redsum[1] + redsum[2] + redsum[3];
    const float inv = 1.0f / sum;
#pragma unroll
    for (int i = 0; i < 9; ++i) Srow[t + i * 256] = f2bf(v[i] * inv);
}

// =====================================================================
extern "C" void kernel_launch(void* const* d_in, const int* in_sizes, int n_in,
                              void* d_out, int out_size, void* d_ws, size_t ws_size,
                              hipStream_t stream)
{
    const float* x  = (const float*)d_in[0];
    const float* Wq = (const float*)d_in[1];
    const float* bq = (const float*)d_in[2];
    const float* Wk = (const float*)d_in[3];
    const float* bk = (const float*)d_in[4];
    const float* Wv = (const float*)d_in[5];
    const float* bv = (const float*)d_in[6];
    const float* Wo = (const float*)d_in[7];
    const float* bo = (const float*)d_in[8];
    float* out = (float*)d_out;

    // workspace (u16 elems):
    //   Wqb/Wkb/Wvb [512x384], Wob [512x512]
    //   xT  [B,N,C]   Qt,Kt [B,N,O]   V [B,O,N]   S [B,N,N]   AOt aliases Qt
    u16* ws = (u16*)d_ws;
    u16* Wqb = ws;
    u16* Wkb = Wqb + WQKV_SZ;
    u16* Wvb = Wkb + WQKV_SZ;
    u16* Wob = Wvb + WQKV_SZ;
    u16* xT  = Wob + WO_SZ;
    const size_t xtsz  = (size_t)B_ * NTOK * CIN;   // 7,077,888
    const size_t qkvsz = (size_t)B_ * NTOK * OCH;   // 9,437,184
    u16* Qt  = xT + xtsz;
    u16* Kt  = Qt + qkvsz;
    u16* Vw  = Kt + qkvsz;
    u16* Sw  = Vw + qkvsz;                          // B*N*N = 42,467,328
    u16* AOt = Qt;                                  // alias: Qt dead after logits
    // total 78,708,736 u16 = 157.4 MB

    dim3 blk(256);

    prep_w_kernel<<<dim3((WTOT / 4 + 255) / 256), blk, 0, stream>>>(
        Wq, Wk, Wv, Wo, Wqb, Wkb, Wvb, Wob);
    transpose_x_kernel<<<dim3(NTOK / 64, CIN / 64, B_), blk, 0, stream>>>(x, xT);

    // Qt[n][o] = sum_c xT[n][c] * Wq[o][c] + bq[o]   (M=NTOK, N=OCH, K=CIN)
    gemm_kernel<2, false, u16><<<dim3(OCH / 128, NTOK / 128, B_), blk, 0, stream>>>(
        xT, Wqb, bq, Qt, CIN, OCH, (long)NTOK * CIN, 0L, (long)NTOK * OCH);
    gemm_kernel<2, false, u16><<<dim3(OCH / 128, NTOK / 128, B_), blk, 0, stream>>>(
        xT, Wkb, bk, Kt, CIN, OCH, (long)NTOK * CIN, 0L, (long)NTOK * OCH);
    // V[o][m] = sum_c Wv[o][c] * xT[m][c] + bv[o]    (M=OCH, N=NTOK, K=CIN)
    gemm_kernel<1, false, u16><<<dim3(NTOK / 128, OCH / 128, B_), blk, 0, stream>>>(
        Wvb, xT, bv, Vw, CIN, NTOK, 0L, (long)NTOK * CIN, (long)OCH * NTOK);

    // S[n][m] = SCALE * sum_o Qt[n][o] * Kt[m][o]    (M=NTOK, N=NTOK, K=OCH)
    gemm_kernel<0, true, u16><<<dim3(NTOK / 128, NTOK / 128, B_), blk, 0, stream>>>(
        Qt, Kt, nullptr, Sw, OCH, NTOK, (long)NTOK * OCH, (long)NTOK * OCH,
        (long)NTOK * NTOK);

    softmax_kernel<<<dim3(B_ * NTOK), blk, 0, stream>>>(Sw);

    // AOt[n][o] = sum_m P[n][m] * V[o][m]            (M=NTOK, N=OCH, K=NTOK)
    gemm_kernel<0, false, u16><<<dim3(OCH / 128, NTOK / 128, B_), blk, 0, stream>>>(
        Sw, Vw, nullptr, AOt, NTOK, OCH, (long)NTOK * NTOK, (long)OCH * NTOK,
        (long)NTOK * OCH);

    // out[p][n] = sum_o Wo[p][o] * AOt[n][o] + bo[p] (M=OCH, N=NTOK, K=OCH)
    gemm_kernel<1, false, float><<<dim3(NTOK / 128, OCH / 128, B_), blk, 0, stream>>>(
        Wob, AOt, bo, out, OCH, NTOK, 0L, (long)NTOK * OCH, (long)OCH * NTOK);
}

// Round 4
// 323.367 us; speedup vs baseline: 6.0369x; 1.1569x over previous
//
#include <hip/hip_runtime.h>
#include <hip/hip_bf16.h>
#include <stdint.h>

// Problem constants (CorrelationModule): x[8,384,48,48], O=512, N=48*48=2304
#define B_    8
#define CIN   384
#define OCH   512
#define NTOK  2304
#define SCALE 0.044194173824159216f  // 1/sqrt(512)

typedef unsigned short u16;
typedef u16   u16x8 __attribute__((ext_vector_type(8)));
typedef u16   u16x4 __attribute__((ext_vector_type(4)));
typedef short s16x8 __attribute__((ext_vector_type(8)));
typedef float f32x4 __attribute__((ext_vector_type(4)));

// ---------- bf16 helpers (bit-level, RNE) ----------
__device__ __forceinline__ float bf2f(u16 u) {
    union { uint32_t i; float f; } v; v.i = ((uint32_t)u) << 16; return v.f;
}
__device__ __forceinline__ u16 f2bf(float f) {
    union { uint32_t i; float f; } v; v.f = f;
    uint32_t r = v.i + 0x7fffu + ((v.i >> 16) & 1u);
    return (u16)(r >> 16);
}

// ---------- async global->LDS (width 16) ----------
typedef __attribute__((address_space(1))) const uint32_t glb_u32;
typedef __attribute__((address_space(3))) uint32_t lds_u32;

// stage a 128x32 u16 tile (row-major, leading dim ld in u16) into
// contiguous LDS [128][32].  global_load_lds: data lands at
// lds_base + lane*16, so lane l covers row chunk*16 + l/4, cols (l%4)*8.
__device__ __forceinline__ void stage_async(const u16* __restrict__ src, int ld,
                                            u16* __restrict__ dst, int t)
{
    const int lane = t & 63;
    const int w = t >> 6;
#pragma unroll
    for (int it = 0; it < 2; ++it) {
        const int chunk = w * 2 + it;            // 0..7
        const int r = chunk * 16 + (lane >> 2);  // 0..127
        const int c = (lane & 3) * 8;            // u16 col
        const u16* gp = src + (size_t)r * ld + c;
        u16* lp = dst + chunk * 512;             // 1024 B per chunk (wave-uniform)
        __builtin_amdgcn_global_load_lds((glb_u32*)gp, (lds_u32*)lp, 16, 0, 0);
    }
}

__device__ __forceinline__ void mfma_core(const u16 (* __restrict__ As)[32],
                                          const u16 (* __restrict__ Bs)[32],
                                          int wm, int wn, int lrow, int kq,
                                          f32x4 acc[4][4])
{
    s16x8 a[4], b[4];
#pragma unroll
    for (int i = 0; i < 4; ++i)
        a[i] = *(const s16x8*)&As[wm + i * 16 + lrow][kq * 8];
#pragma unroll
    for (int j = 0; j < 4; ++j)
        b[j] = *(const s16x8*)&Bs[wn + j * 16 + lrow][kq * 8];
#pragma unroll
    for (int i = 0; i < 4; ++i)
#pragma unroll
        for (int j = 0; j < 4; ++j)
            acc[i][j] = __builtin_amdgcn_mfma_f32_16x16x32_bf16(a[i], b[j], acc[i][j], 0, 0, 0);
}

// =====================================================================
// Kernel 0a: weight cast fp32 -> bf16
// =====================================================================
#define WQKV_SZ (OCH * CIN)
#define WO_SZ   (OCH * OCH)
#define WTOT    (3 * WQKV_SZ + WO_SZ)

__global__ __launch_bounds__(256) void prep_w_kernel(
    const float* __restrict__ Wq, const float* __restrict__ Wk,
    const float* __restrict__ Wv, const float* __restrict__ Wo,
    u16* __restrict__ Wqb, u16* __restrict__ Wkb,
    u16* __restrict__ Wvb, u16* __restrict__ Wob)
{
    const int i4 = (blockIdx.x * 256 + threadIdx.x) * 4;
    if (i4 >= WTOT) return;
    const float* src; u16* dst; int off;
    if      (i4 < WQKV_SZ)     { src = Wq; dst = Wqb; off = i4; }
    else if (i4 < 2 * WQKV_SZ) { src = Wk; dst = Wkb; off = i4 - WQKV_SZ; }
    else if (i4 < 3 * WQKV_SZ) { src = Wv; dst = Wvb; off = i4 - 2 * WQKV_SZ; }
    else                       { src = Wo; dst = Wob; off = i4 - 3 * WQKV_SZ; }
    float4 v = *(const float4*)(src + off);
    u16x4 o;
    o.x = f2bf(v.x); o.y = f2bf(v.y); o.z = f2bf(v.z); o.w = f2bf(v.w);
    *(u16x4*)(dst + off) = o;
}

// =====================================================================
// Kernel 0b: transpose x [B,C,N] fp32 -> xT [B,N,C] bf16.  64x64 tiles.
// =====================================================================
__global__ __launch_bounds__(256) void transpose_x_kernel(
    const float* __restrict__ x, u16* __restrict__ xT)
{
    const int n0 = blockIdx.x * 64;
    const int c0 = blockIdx.y * 64;
    const int b  = blockIdx.z;
    const float* X = x + (size_t)b * CIN * NTOK;

    __shared__ float Ts[64][66];

    const int t = threadIdx.x;
#pragma unroll
    for (int rep = 0; rep < 4; ++rep) {
        const int cr = (t >> 4) + rep * 16;
        const int n4 = (t & 15) * 4;
        float4 v = *(const float4*)(X + (size_t)(c0 + cr) * NTOK + n0 + n4);
        *(float2*)&Ts[cr][n4]     = make_float2(v.x, v.y);
        *(float2*)&Ts[cr][n4 + 2] = make_float2(v.z, v.w);
    }
    __syncthreads();

    u16* O = xT + (size_t)b * NTOK * CIN;
#pragma unroll
    for (int rep = 0; rep < 2; ++rep) {
        const int nr = (t >> 3) + rep * 32;
        const int c8 = (t & 7) * 8;
        u16 tmp[8];
#pragma unroll
        for (int j = 0; j < 8; ++j) tmp[j] = f2bf(Ts[c8 + j][nr]);
        *(u16x8*)(O + (size_t)(n0 + nr) * CIN + c0 + c8) = *(const u16x8*)tmp;
    }
}

// =====================================================================
// Generic MFMA GEMM: C[m][n] = sum_k A[m][k]*B[n][k] (+bias)
// 128x128 tile, BK=32, async staging.  BIAS: 0 none, 1 row, 2 col.
// =====================================================================
template <int BIAS, typename OutT>
__global__ __launch_bounds__(256) void gemm_kernel(
    const u16* __restrict__ Ag, const u16* __restrict__ Bg,
    const float* __restrict__ bias, OutT* __restrict__ Cg,
    int K, int N, long sA, long sB, long sC)
{
    const int n0 = blockIdx.x * 128;
    const int m0 = blockIdx.y * 128;
    const int z  = blockIdx.z;
    const u16* A  = Ag + (size_t)z * sA + (size_t)m0 * K;
    const u16* Bp = Bg + (size_t)z * sB + (size_t)n0 * K;
    OutT* C = Cg + (size_t)z * sC;

    __shared__ u16 As[128][32];
    __shared__ u16 Bs[128][32];

    const int t = threadIdx.x;
    const int w = t >> 6, ln = t & 63;
    const int wm = (w & 1) * 64, wn = (w >> 1) * 64;
    const int lrow = ln & 15, kq = ln >> 4;

    f32x4 acc[4][4] = {};

    for (int k0 = 0; k0 < K; k0 += 32) {
        stage_async(A + k0, K, &As[0][0], t);
        stage_async(Bp + k0, K, &Bs[0][0], t);
        __syncthreads();
        mfma_core(As, Bs, wm, wn, lrow, kq, acc);
        __syncthreads();
    }

#pragma unroll
    for (int i = 0; i < 4; ++i) {
        const int row = m0 + wm + i * 16 + kq * 4;
#pragma unroll
        for (int r = 0; r < 4; ++r) {
            float badd = 0.f;
            if (BIAS == 1) badd = bias[row + r];
#pragma unroll
            for (int j = 0; j < 4; ++j) {
                const int col = n0 + wn + j * 16 + lrow;
                float v = acc[i][j][r];
                if (BIAS == 1) v += badd;
                if (BIAS == 2) v += bias[col];
                if constexpr (sizeof(OutT) == 2)
                    C[(size_t)(row + r) * N + col] = f2bf(v);
                else
                    C[(size_t)(row + r) * N + col] = v;
            }
        }
    }
}

// =====================================================================
// Logits+exp kernel: E[n][m] = exp(SCALE * Qt[n]. Kt[m]), bf16 store;
// rowsumG[z][n] += partial row sums (fp32, device atomics).
// =====================================================================
__global__ __launch_bounds__(256) void logits_exp_kernel(
    const u16* __restrict__ Qt, const u16* __restrict__ Kt,
    u16* __restrict__ Ew, float* __restrict__ rowsumG)
{
    const int n0 = blockIdx.x * 128;   // cols m (Kt tokens)
    const int m0 = blockIdx.y * 128;   // rows n (Qt tokens)
    const int z  = blockIdx.z;
    const u16* A  = Qt + (size_t)z * NTOK * OCH + (size_t)m0 * OCH;
    const u16* Bp = Kt + (size_t)z * NTOK * OCH + (size_t)n0 * OCH;

    __shared__ u16 As[128][32];
    __shared__ u16 Bs[128][32];
    __shared__ float rowsumL[128];

    const int t = threadIdx.x;
    const int w = t >> 6, ln = t & 63;
    const int wm = (w & 1) * 64, wn = (w >> 1) * 64;
    const int lrow = ln & 15, kq = ln >> 4;

    if (t < 128) rowsumL[t] = 0.f;

    f32x4 acc[4][4] = {};

    for (int k0 = 0; k0 < OCH; k0 += 32) {
        stage_async(A + k0, OCH, &As[0][0], t);
        stage_async(Bp + k0, OCH, &Bs[0][0], t);
        __syncthreads();
        mfma_core(As, Bs, wm, wn, lrow, kq, acc);
        __syncthreads();
    }

    u16* E = Ew + (size_t)z * NTOK * NTOK;
#pragma unroll
    for (int i = 0; i < 4; ++i) {
        const int row = m0 + wm + i * 16 + kq * 4;
#pragma unroll
        for (int r = 0; r < 4; ++r) {
            float part = 0.f;
#pragma unroll
            for (int j = 0; j < 4; ++j) {
                const int col = n0 + wn + j * 16 + lrow;
                float e = __expf(acc[i][j][r] * SCALE);
                part += e;
                E[(size_t)(row + r) * NTOK + col] = f2bf(e);
            }
            // reduce over the 16-lane group (lrow) -> lane lrow==0
            part += __shfl_xor(part, 1);
            part += __shfl_xor(part, 2);
            part += __shfl_xor(part, 4);
            part += __shfl_xor(part, 8);
            if (lrow == 0) atomicAdd(&rowsumL[wm + i * 16 + kq * 4 + r], part);
        }
    }
    __syncthreads();
    if (t < 128) atomicAdd(&rowsumG[(size_t)z * NTOK + m0 + t], rowsumL[t]);
}

// =====================================================================
// PV kernel: AOt[n][o] = (sum_m E[n][m] * V[o][m]) / rowsumG[z][n]
// =====================================================================
__global__ __launch_bounds__(256) void pv_div_kernel(
    const u16* __restrict__ Ew, const u16* __restrict__ Vw,
    const float* __restrict__ rowsumG, u16* __restrict__ AOt)
{
    const int n0 = blockIdx.x * 128;   // channel cols o
    const int m0 = blockIdx.y * 128;   // token rows n
    const int z  = blockIdx.z;
    const u16* A  = Ew + (size_t)z * NTOK * NTOK + (size_t)m0 * NTOK;
    const u16* Bp = Vw + (size_t)z * OCH * NTOK + (size_t)n0 * NTOK;

    __shared__ u16 As[128][32];
    __shared__ u16 Bs[128][32];

    const int t = threadIdx.x;
    const int w = t >> 6, ln = t & 63;
    const int wm = (w & 1) * 64, wn = (w >> 1) * 64;
    const int lrow = ln & 15, kq = ln >> 4;

    f32x4 acc[4][4] = {};

    for (int k0 = 0; k0 < NTOK; k0 += 32) {
        stage_async(A + k0, NTOK, &As[0][0], t);
        stage_async(Bp + k0, NTOK, &Bs[0][0], t);
        __syncthreads();
        mfma_core(As, Bs, wm, wn, lrow, kq, acc);
        __syncthreads();
    }

    u16* AO = AOt + (size_t)z * NTOK * OCH;
#pragma unroll
    for (int i = 0; i < 4; ++i) {
        const int row = m0 + wm + i * 16 + kq * 4;
#pragma unroll
        for (int r = 0; r < 4; ++r) {
            const float inv = 1.0f / rowsumG[(size_t)z * NTOK + row + r];
#pragma unroll
            for (int j = 0; j < 4; ++j) {
                const int col = n0 + wn + j * 16 + lrow;
                AO[(size_t)(row + r) * OCH + col] = f2bf(acc[i][j][r] * inv);
            }
        }
    }
}

// =====================================================================
extern "C" void kernel_launch(void* const* d_in, const int* in_sizes, int n_in,
                              void* d_out, int out_size, void* d_ws, size_t ws_size,
                              hipStream_t stream)
{
    const float* x  = (const float*)d_in[0];
    const float* Wq = (const float*)d_in[1];
    const float* bq = (const float*)d_in[2];
    const float* Wk = (const float*)d_in[3];
    const float* bk = (const float*)d_in[4];
    const float* Wv = (const float*)d_in[5];
    const float* bv = (const float*)d_in[6];
    const float* Wo = (const float*)d_in[7];
    const float* bo = (const float*)d_in[8];
    float* out = (float*)d_out;

    // workspace (u16 elems):
    //   Wqb/Wkb/Wvb, Wob | xT [B,N,C] | Qt,Kt [B,N,O] | V [B,O,N] | E [B,N,N]
    //   rowsumG (fp32, B*N) | AOt aliases Qt (dead after logits)
    u16* ws = (u16*)d_ws;
    u16* Wqb = ws;
    u16* Wkb = Wqb + WQKV_SZ;
    u16* Wvb = Wkb + WQKV_SZ;
    u16* Wob = Wvb + WQKV_SZ;
    u16* xT  = Wob + WO_SZ;
    const size_t xtsz  = (size_t)B_ * NTOK * CIN;
    const size_t qkvsz = (size_t)B_ * NTOK * OCH;
    u16* Qt  = xT + xtsz;
    u16* Kt  = Qt + qkvsz;
    u16* Vw  = Kt + qkvsz;
    u16* Ew  = Vw + qkvsz;                          // B*N*N
    float* rowsumG = (float*)(Ew + (size_t)B_ * NTOK * NTOK);
    u16* AOt = Qt;
    // total approx 157.5 MB

    dim3 blk(256);

    prep_w_kernel<<<dim3((WTOT / 4 + 255) / 256), blk, 0, stream>>>(
        Wq, Wk, Wv, Wo, Wqb, Wkb, Wvb, Wob);
    transpose_x_kernel<<<dim3(NTOK / 64, CIN / 64, B_), blk, 0, stream>>>(x, xT);
    hipMemsetAsync(rowsumG, 0, (size_t)B_ * NTOK * sizeof(float), stream);

    // Qt[n][o] = xT[n]. Wq[o] + bq[o]
    gemm_kernel<2, u16><<<dim3(OCH / 128, NTOK / 128, B_), blk, 0, stream>>>(
        xT, Wqb, bq, Qt, CIN, OCH, (long)NTOK * CIN, 0L, (long)NTOK * OCH);
    gemm_kernel<2, u16><<<dim3(OCH / 128, NTOK / 128, B_), blk, 0, stream>>>(
        xT, Wkb, bk, Kt, CIN, OCH, (long)NTOK * CIN, 0L, (long)NTOK * OCH);
    // V[o][m] = Wv[o] . xT[m] + bv[o]
    gemm_kernel<1, u16><<<dim3(NTOK / 128, OCH / 128, B_), blk, 0, stream>>>(
        Wvb, xT, bv, Vw, CIN, NTOK, 0L, (long)NTOK * CIN, (long)OCH * NTOK);

    // E = exp(scale * Qt.Kt^T), rowsumG += row sums
    logits_exp_kernel<<<dim3(NTOK / 128, NTOK / 128, B_), blk, 0, stream>>>(
        Qt, Kt, Ew, rowsumG);

    // AOt[n][o] = (E[n] . V[o]) / rowsum[n]
    pv_div_kernel<<<dim3(OCH / 128, NTOK / 128, B_), blk, 0, stream>>>(
        Ew, Vw, rowsumG, AOt);

    // out[p][n] = Wo[p] . AOt[n] + bo[p]
    gemm_kernel<1, float><<<dim3(NTOK / 128, OCH / 128, B_), blk, 0, stream>>>(
        Wob, AOt, bo, out, OCH, NTOK, 0L, (long)NTOK * OCH, (long)OCH * NTOK);
}